// Round 1
// baseline (2693.219 us; speedup 1.0000x reference)
//
#include <hip/hip_runtime.h>

#define BB 16
#define TT 128
#define HH 34
#define WW 34
#define HWSZ (HH*WW)                 // 1156
#define NP1 (BB*TT*HH*WW)            // 2367488
#define TD 64
#define HD 17
#define WD 17
#define NP2 (BB*TD*HD*WD)            // 295936
#define CAP1 262144
#define CAP2 131072
#define G3 1024
#define P3 32

// ---------------- mask1: active input positions (b,t,h,w) ----------------
__global__ void k_mask1(const float* __restrict__ x, int* __restrict__ idx1,
                        int* __restrict__ list1, int* __restrict__ counter1) {
  int i = blockIdx.x * blockDim.x + threadIdx.x;
  if (i >= NP1) return;
  int hw = i % HWSZ;
  int bt = i / HWSZ;
  const float* px = x + (size_t)bt * 2 * HWSZ + hw;
  float a = fabsf(px[0]) + fabsf(px[HWSZ]);
  bool act = a > 0.0f;
  unsigned long long m = __ballot(act);
  int lane = threadIdx.x & 63;
  int cntw = __popcll(m);
  int base = 0;
  if (lane == 0 && cntw) base = atomicAdd(counter1, cntw);
  base = __shfl(base, 0);
  if (act) {
    int pos = base + __popcll(m & ((1ull << lane) - 1ull));
    if (pos < CAP1) { idx1[i] = pos; list1[pos] = i; }
    else idx1[i] = -1;
  } else {
    idx1[i] = -1;
  }
}

// ---------------- mask2: pooled mask + count ----------------
__global__ void k_mask2(const int* __restrict__ idx1, int* __restrict__ idx2,
                        int* __restrict__ list2, int* __restrict__ counter2,
                        float* __restrict__ cnt) {
  int i = blockIdx.x * blockDim.x + threadIdx.x;
  if (i >= NP2) return;
  int ow = i % WD; int r = i / WD;
  int oh = r % HD; r /= HD;
  int od = r % TD; int b = r / TD;
  bool act = false;
  for (int dt = 0; dt < 2; dt++)
    for (int dh = 0; dh < 2; dh++)
      for (int dw = 0; dw < 2; dw++) {
        int t = od * 2 + dt, h = oh * 2 + dh, w = ow * 2 + dw;
        int lin = ((b * TT + t) * HH + h) * WW + w;
        if (idx1[lin] >= 0) act = true;
      }
  unsigned long long m = __ballot(act);
  int lane = threadIdx.x & 63;
  int cntw = __popcll(m);
  int base = 0;
  if (lane == 0 && cntw) {
    base = atomicAdd(counter2, cntw);
    atomicAdd(&cnt[b], (float)cntw);   // b is wave-uniform (18496 per b, mult of 64)
  }
  base = __shfl(base, 0);
  if (act) {
    int pos = base + __popcll(m & ((1ull << lane) - 1ull));
    if (pos < CAP2) { idx2[i] = pos; list2[pos] = i; }
    else idx2[i] = -1;
  } else {
    idx2[i] = -1;
  }
}

// ---------------- conv1 at active positions, wave per position ----------------
__global__ __launch_bounds__(256) void k_conv1(
    const float* __restrict__ x, const float* __restrict__ w1,
    const int* __restrict__ list1, const int* __restrict__ counter1,
    float* __restrict__ h1c) {
  __shared__ float w1s[8000];
  for (int j = threadIdx.x; j < 8000; j += 256) w1s[j] = w1[j];
  __syncthreads();
  int count1 = min(*counter1, CAP1);
  int lane = threadIdx.x & 63;
  int wid = blockIdx.x * 4 + (threadIdx.x >> 6);
  int nw = gridDim.x * 4;
  int oc = lane & 31, c = lane >> 5;
  const float* wrow = &w1s[(oc * 2 + c) * 125];
  for (int p = wid; p < count1; p += nw) {
    int lin = list1[p];
    int w_ = lin % WW; int r = lin / WW;
    int h_ = r % HH; r /= HH;
    int t_ = r % TT; int b_ = r / TT;
    const float* xb = x + (size_t)b_ * TT * 2 * HWSZ;
    float acc = 0.f;
    int k = 0;
    for (int kt = 0; kt < 5; kt++) {
      int t2 = t_ + kt - 2;
      bool tv = (unsigned)t2 < TT;
      for (int kh = 0; kh < 5; kh++) {
        int h2 = h_ + kh - 2;
        bool hv = tv && ((unsigned)h2 < HH);
        for (int kw = 0; kw < 5; kw++, k++) {
          int w2_ = w_ + kw - 2;
          if (hv && (unsigned)w2_ < WW) {
            float v = xb[(size_t)(t2 * 2 + c) * HWSZ + h2 * WW + w2_];
            acc += v * wrow[k];
          }
        }
      }
    }
    float other = __shfl_down(acc, 32);
    if (lane < 32) h1c[(size_t)p * 32 + oc] = acc + other;
  }
}

// ---------------- weight transposes ----------------
__global__ void k_tw2(const float* __restrict__ w2, float* __restrict__ w2t) {
  int i = blockIdx.x * blockDim.x + threadIdx.x;
  if (i >= 64 * 32 * 125) return;
  int k = i % 125; int r = i / 125;
  int c = r % 32; int oc = r / 32;
  w2t[(k * 32 + c) * 64 + oc] = w2[i];
}
__global__ void k_tw3(const float* __restrict__ w3, float* __restrict__ w3t) {
  int i = blockIdx.x * blockDim.x + threadIdx.x;
  if (i >= 128 * 64 * 27) return;
  int k = i % 27; int r = i / 27;
  int c = r % 64; int oc = r / 64;
  w3t[(k * 64 + c) * 128 + oc] = w3[i];
}

// ---------------- conv2: wave per active pooled position, skip zero input taps ----------------
__global__ __launch_bounds__(64) void k_conv2(
    const float* __restrict__ h1c, const float* __restrict__ w2t,
    const int* __restrict__ idx1, const int* __restrict__ list2,
    const int* __restrict__ counter2, float* __restrict__ h2c) {
  int count2 = min(*counter2, CAP2);
  int oc = threadIdx.x;  // 0..63
  for (int p = blockIdx.x; p < count2; p += gridDim.x) {
    int pos = list2[p];
    int ow = pos % WD; int r = pos / WD;
    int oh = r % HD; r /= HD;
    int od = r % TD; int b = r / TD;
    float acc = 0.f;
    for (int kt = 0; kt < 5; kt++) {
      int t = od * 2 + kt - 2;
      if ((unsigned)t >= TT) continue;
      for (int kh = 0; kh < 5; kh++) {
        int h = oh * 2 + kh - 2;
        if ((unsigned)h >= HH) continue;
        for (int kw = 0; kw < 5; kw++) {
          int w = ow * 2 + kw - 2;
          if ((unsigned)w >= WW) continue;
          int lin = ((b * TT + t) * HH + h) * WW + w;
          int ip = idx1[lin];
          if (ip < 0) continue;
          const float* vrow = &h1c[(size_t)ip * 32];
          const float* wrow = &w2t[(size_t)(kt * 25 + kh * 5 + kw) * 32 * 64 + oc];
          #pragma unroll
          for (int c = 0; c < 32; c++) acc += vrow[c] * wrow[c * 64];
        }
      }
    }
    h2c[(size_t)p * 64 + oc] = fmaxf(acc, 0.f);
  }
}

// ---------------- conv3 + fused masked pooling (per-block partials) ----------------
__global__ __launch_bounds__(128) void k_conv3(
    const float* __restrict__ h2c, const float* __restrict__ w3t,
    const int* __restrict__ idx2, const int* __restrict__ list2,
    const int* __restrict__ counter2, float* __restrict__ partial) {
  __shared__ float intap[64][P3];   // [c][p]  8KB
  __shared__ float pools[16 * 128]; // 8KB
  __shared__ int meta[P3];
  int tid = threadIdx.x;
  int oc = tid;  // 0..127
  for (int j = tid; j < 2048; j += 128) pools[j] = 0.f;
  int count2 = min(*counter2, CAP2);
  int nchunk = (count2 + P3 - 1) / P3;
  for (int ch = blockIdx.x; ch < nchunk; ch += gridDim.x) {
    int base = ch * P3;
    __syncthreads();
    if (tid < P3) {
      int p = base + tid;
      meta[tid] = (p < count2) ? list2[p] : -1;
    }
    float acc[P3];
    #pragma unroll
    for (int p = 0; p < P3; p++) acc[p] = 0.f;
    for (int tap = 0; tap < 27; tap++) {
      int dt = tap / 9 - 1, dh = (tap / 3) % 3 - 1, dw = tap % 3 - 1;
      __syncthreads();
      {
        int p = tid >> 2;
        int cq = (tid & 3) * 16;
        int pos = meta[p];
        int row = -1;
        if (pos >= 0) {
          int ow = pos % WD; int r = pos / WD;
          int oh = r % HD; r /= HD;
          int od = r % TD; int b = r / TD;
          int t = od + dt, h = oh + dh, w = ow + dw;
          if ((unsigned)t < TD && (unsigned)h < HD && (unsigned)w < WD)
            row = idx2[((b * TD + t) * HD + h) * WD + w];
        }
        if (row >= 0) {
          const float* src = &h2c[(size_t)row * 64 + cq];
          #pragma unroll
          for (int j = 0; j < 16; j++) intap[cq + j][p] = src[j];
        } else {
          #pragma unroll
          for (int j = 0; j < 16; j++) intap[cq + j][p] = 0.f;
        }
      }
      __syncthreads();
      for (int c = 0; c < 64; c++) {
        float wv = w3t[((size_t)tap * 64 + c) * 128 + oc];
        const float4* vp = (const float4*)&intap[c][0];
        #pragma unroll
        for (int q = 0; q < P3 / 4; q++) {
          float4 v = vp[q];
          acc[q * 4 + 0] += v.x * wv;
          acc[q * 4 + 1] += v.y * wv;
          acc[q * 4 + 2] += v.z * wv;
          acc[q * 4 + 3] += v.w * wv;
        }
      }
    }
    __syncthreads();
    #pragma unroll
    for (int p = 0; p < P3; p++) {
      int pos = meta[p];
      if (pos >= 0) {
        int b = pos / (TD * HD * WD);
        pools[b * 128 + oc] += fmaxf(acc[p], 0.f);
      }
    }
  }
  __syncthreads();
  for (int j = tid; j < 2048; j += 128)
    partial[(size_t)blockIdx.x * 2048 + j] = pools[j];
}

// ---------------- final: reduce partials, divide, linear, relu, softmax ----------------
__global__ void k_final(const float* __restrict__ partial, const float* __restrict__ cnt,
                        const float* __restrict__ wl, const float* __restrict__ bl,
                        float* __restrict__ out) {
  __shared__ float pr[128];
  __shared__ float lg[10];
  int b = blockIdx.x;
  int tid = threadIdx.x;
  float s = 0.f;
  for (int g = 0; g < G3; g++) s += partial[(size_t)g * 2048 + b * 128 + tid];
  float c = fmaxf(cnt[b], 1.0f);
  pr[tid] = s / c;
  __syncthreads();
  if (tid < 10) {
    float acc = bl[tid];
    for (int j = 0; j < 128; j++) acc += pr[j] * wl[tid * 128 + j];
    lg[tid] = fmaxf(acc, 0.f);
  }
  __syncthreads();
  if (tid == 0) {
    float mx = lg[0];
    for (int k = 1; k < 10; k++) mx = fmaxf(mx, lg[k]);
    float se = 0.f;
    for (int k = 0; k < 10; k++) se += expf(lg[k] - mx);
    for (int k = 0; k < 10; k++) out[b * 10 + k] = expf(lg[k] - mx) / se;
  }
}

extern "C" void kernel_launch(void* const* d_in, const int* in_sizes, int n_in,
                              void* d_out, int out_size, void* d_ws, size_t ws_size,
                              hipStream_t stream) {
  const float* x  = (const float*)d_in[0];
  const float* w1 = (const float*)d_in[1];
  const float* w2 = (const float*)d_in[2];
  const float* w3 = (const float*)d_in[3];
  const float* wl = (const float*)d_in[4];
  const float* bl = (const float*)d_in[5];
  float* out = (float*)d_out;

  float* ws = (float*)d_ws;
  int* counter1 = (int*)(ws + 0);
  int* counter2 = (int*)(ws + 1);
  float* cnt = ws + 16;
  size_t off = 64;
  int* idx1 = (int*)(ws + off); off += NP1;
  int* list1 = (int*)(ws + off); off += CAP1;
  float* h1c = ws + off; off += (size_t)CAP1 * 32;
  int* idx2 = (int*)(ws + off); off += NP2;
  int* list2 = (int*)(ws + off); off += CAP2;
  float* h2c = ws + off; off += (size_t)CAP2 * 64;
  float* w2t = ws + off; off += 256000;
  float* w3t = ws + off; off += 221184;
  float* partial = ws + off; off += (size_t)G3 * 2048;

  hipMemsetAsync(d_ws, 0, 256, stream);  // counters + cnt

  k_tw2<<<(256000 + 255) / 256, 256, 0, stream>>>(w2, w2t);
  k_tw3<<<(221184 + 255) / 256, 256, 0, stream>>>(w3, w3t);
  k_mask1<<<(NP1 + 255) / 256, 256, 0, stream>>>(x, idx1, list1, counter1);
  k_conv1<<<2048, 256, 0, stream>>>(x, w1, list1, counter1, h1c);
  k_mask2<<<(NP2 + 255) / 256, 256, 0, stream>>>(idx1, idx2, list2, counter2, cnt);
  k_conv2<<<8192, 64, 0, stream>>>(h1c, w2t, idx1, list2, counter2, h2c);
  k_conv3<<<G3, 128, 0, stream>>>(h2c, w3t, idx2, list2, counter2, partial);
  k_final<<<16, 128, 0, stream>>>(partial, cnt, wl, bl, out);
}

// Round 2
// 1486.957 us; speedup vs baseline: 1.8112x; 1.8112x over previous
//
#include <hip/hip_runtime.h>

#define BB 16
#define TT 128
#define HH 34
#define WW 34
#define HWSZ (HH*WW)                 // 1156
#define NP1 (BB*TT*HH*WW)            // 2367488
#define TD 64
#define HD 17
#define WD 17
#define NP2 (BB*TD*HD*WD)            // 295936
#define CAP1 262144
#define CAP2 131072

typedef __attribute__((ext_vector_type(8))) short bf16x8;
typedef __attribute__((ext_vector_type(4))) float f32x4;

__device__ inline unsigned short f2bf(float f) {
  unsigned u = __float_as_uint(f);
  unsigned r = (u + 0x7fff + ((u >> 16) & 1)) >> 16;
  return (unsigned short)r;
}
__device__ inline float bf2f(unsigned short s) {
  return __uint_as_float((unsigned)s << 16);
}

// ---------------- mask1: active input positions (b,t,h,w) ----------------
__global__ void k_mask1(const float* __restrict__ x, int* __restrict__ idx1,
                        int* __restrict__ list1, int* __restrict__ counter1) {
  int i = blockIdx.x * blockDim.x + threadIdx.x;
  if (i >= NP1) return;
  int hw = i % HWSZ;
  int bt = i / HWSZ;
  const float* px = x + (size_t)bt * 2 * HWSZ + hw;
  float a = fabsf(px[0]) + fabsf(px[HWSZ]);
  bool act = a > 0.0f;
  unsigned long long m = __ballot(act);
  int lane = threadIdx.x & 63;
  int cntw = __popcll(m);
  int base = 0;
  if (lane == 0 && cntw) base = atomicAdd(counter1, cntw);
  base = __shfl(base, 0);
  if (act) {
    int pos = base + __popcll(m & ((1ull << lane) - 1ull));
    if (pos < CAP1) { idx1[i] = pos; list1[pos] = i; }
    else idx1[i] = -1;
  } else {
    idx1[i] = -1;
  }
}

// ---------------- mask2: pooled mask + count ----------------
__global__ void k_mask2(const int* __restrict__ idx1, int* __restrict__ idx2,
                        int* __restrict__ list2, int* __restrict__ counter2,
                        float* __restrict__ cnt) {
  int i = blockIdx.x * blockDim.x + threadIdx.x;
  if (i >= NP2) return;
  int ow = i % WD; int r = i / WD;
  int oh = r % HD; r /= HD;
  int od = r % TD; int b = r / TD;
  bool act = false;
  for (int dt = 0; dt < 2; dt++)
    for (int dh = 0; dh < 2; dh++)
      for (int dw = 0; dw < 2; dw++) {
        int t = od * 2 + dt, h = oh * 2 + dh, w = ow * 2 + dw;
        int lin = ((b * TT + t) * HH + h) * WW + w;
        if (idx1[lin] >= 0) act = true;
      }
  unsigned long long m = __ballot(act);
  int lane = threadIdx.x & 63;
  int cntw = __popcll(m);
  int base = 0;
  if (lane == 0 && cntw) {
    base = atomicAdd(counter2, cntw);
    atomicAdd(&cnt[b], (float)cntw);   // b is wave-uniform
  }
  base = __shfl(base, 0);
  if (act) {
    int pos = base + __popcll(m & ((1ull << lane) - 1ull));
    if (pos < CAP2) { idx2[i] = pos; list2[pos] = i; }
    else idx2[i] = -1;
  } else {
    idx2[i] = -1;
  }
}

// ---------------- conv1 at active positions, wave per position ----------------
__global__ __launch_bounds__(256) void k_conv1(
    const float* __restrict__ x, const float* __restrict__ w1,
    const int* __restrict__ list1, const int* __restrict__ counter1,
    unsigned short* __restrict__ h1c) {
  __shared__ float w1s[8000];
  for (int j = threadIdx.x; j < 8000; j += 256) w1s[j] = w1[j];
  __syncthreads();
  int count1 = min(*counter1, CAP1);
  int lane = threadIdx.x & 63;
  int wid = blockIdx.x * 4 + (threadIdx.x >> 6);
  int nw = gridDim.x * 4;
  int oc = lane & 31, c = lane >> 5;
  const float* wrow = &w1s[(oc * 2 + c) * 125];
  for (int p = wid; p < count1; p += nw) {
    int lin = list1[p];
    int w_ = lin % WW; int r = lin / WW;
    int h_ = r % HH; r /= HH;
    int t_ = r % TT; int b_ = r / TT;
    const float* xb = x + (size_t)b_ * TT * 2 * HWSZ;
    float acc = 0.f;
    int k = 0;
    for (int kt = 0; kt < 5; kt++) {
      int t2 = t_ + kt - 2;
      bool tv = (unsigned)t2 < TT;
      for (int kh = 0; kh < 5; kh++) {
        int h2 = h_ + kh - 2;
        bool hv = tv && ((unsigned)h2 < HH);
        for (int kw = 0; kw < 5; kw++, k++) {
          int w2_ = w_ + kw - 2;
          if (hv && (unsigned)w2_ < WW) {
            float v = xb[(size_t)(t2 * 2 + c) * HWSZ + h2 * WW + w2_];
            acc += v * wrow[k];
          }
        }
      }
    }
    float other = __shfl_down(acc, 32);
    if (lane < 32) h1c[(size_t)p * 32 + oc] = f2bf(acc + other);
  }
}

// ---------------- weight transposes to bf16 [tap][oc][c] ----------------
__global__ void k_tw2b(const float* __restrict__ w2, unsigned short* __restrict__ w2b) {
  int i = blockIdx.x * blockDim.x + threadIdx.x;
  if (i >= 125 * 64 * 32) return;
  int c = i & 31; int r = i >> 5;
  int oc = r & 63; int tap = r >> 6;
  w2b[i] = f2bf(w2[((size_t)oc * 32 + c) * 125 + tap]);
}
__global__ void k_tw3b(const float* __restrict__ w3, unsigned short* __restrict__ w3b) {
  int i = blockIdx.x * blockDim.x + threadIdx.x;
  if (i >= 27 * 128 * 64) return;
  int c = i & 63; int r = i >> 6;
  int oc = r & 127; int tap = r >> 7;
  w3b[i] = f2bf(w3[((size_t)oc * 64 + c) * 27 + tap]);
}

// ---------------- conv2 via MFMA: chunk of 64 positions, K=125 taps x 32c ----------------
#define S2 40   // LDS row stride in shorts (80B = 5*16B, odd multiple -> conflict-free-ish)
__global__ __launch_bounds__(256) void k_conv2m(
    const unsigned short* __restrict__ h1c,   // [CAP1][32] bf16
    const unsigned short* __restrict__ w2b,   // [125][64][32] bf16
    const int* __restrict__ idx1,
    const int* __restrict__ list2, const int* __restrict__ counter2,
    unsigned short* __restrict__ h2c) {       // [CAP2][64] bf16
  __shared__ __align__(16) unsigned short As[64 * S2];
  __shared__ __align__(16) unsigned short Bs[64 * S2];
  __shared__ int meta[64];
  int tid = threadIdx.x;
  int lane = tid & 63, wid = tid >> 6;
  int fr = lane & 15, fq = lane >> 4;
  int wr = (wid >> 1) * 32, wc = (wid & 1) * 32;
  int count2 = min(*counter2, CAP2);
  int nchunk = (count2 + 63) >> 6;
  int spos = tid >> 2, sq = tid & 3;          // staging: 4 threads per row
  for (int ch = blockIdx.x; ch < nchunk; ch += gridDim.x) {
    __syncthreads();
    if (tid < 64) {
      int p = ch * 64 + tid;
      meta[tid] = (p < count2) ? list2[p] : -1;
    }
    __syncthreads();
    int mpos = meta[spos];
    int b_ = 0, od = 0, oh = 0, ow = 0;
    if (mpos >= 0) {
      ow = mpos % WD; int r = mpos / WD;
      oh = r % HD; r /= HD;
      od = r % TD; b_ = r / TD;
    }
    f32x4 acc[2][2];
    #pragma unroll
    for (int i = 0; i < 2; i++)
      #pragma unroll
      for (int j = 0; j < 2; j++) acc[i][j] = (f32x4){0.f, 0.f, 0.f, 0.f};
    for (int tap = 0; tap < 125; tap++) {
      int kt = tap / 25, kh = (tap / 5) % 5, kw = tap % 5;
      __syncthreads();
      {
        int row = -1;
        if (mpos >= 0) {
          int t = od * 2 + kt - 2, h = oh * 2 + kh - 2, w = ow * 2 + kw - 2;
          if ((unsigned)t < TT && (unsigned)h < HH && (unsigned)w < WW)
            row = idx1[((b_ * TT + t) * HH + h) * WW + w];
        }
        int4 v = {0, 0, 0, 0};
        if (row >= 0) v = *(const int4*)(h1c + (size_t)row * 32 + sq * 8);
        *(int4*)(As + spos * S2 + sq * 8) = v;
        *(int4*)(Bs + spos * S2 + sq * 8) =
            *(const int4*)(w2b + ((size_t)tap * 64 + spos) * 32 + sq * 8);
      }
      __syncthreads();
      const unsigned short* ap = As + (wr + fr) * S2 + fq * 8;
      const unsigned short* bp = Bs + (wc + fr) * S2 + fq * 8;
      bf16x8 a0 = *(const bf16x8*)ap;
      bf16x8 a1 = *(const bf16x8*)(ap + 16 * S2);
      bf16x8 b0 = *(const bf16x8*)bp;
      bf16x8 b1 = *(const bf16x8*)(bp + 16 * S2);
      acc[0][0] = __builtin_amdgcn_mfma_f32_16x16x32_bf16(a0, b0, acc[0][0], 0, 0, 0);
      acc[0][1] = __builtin_amdgcn_mfma_f32_16x16x32_bf16(a0, b1, acc[0][1], 0, 0, 0);
      acc[1][0] = __builtin_amdgcn_mfma_f32_16x16x32_bf16(a1, b0, acc[1][0], 0, 0, 0);
      acc[1][1] = __builtin_amdgcn_mfma_f32_16x16x32_bf16(a1, b1, acc[1][1], 0, 0, 0);
    }
    int base = ch * 64;
    #pragma unroll
    for (int mi = 0; mi < 2; mi++)
      #pragma unroll
      for (int ni = 0; ni < 2; ni++)
        #pragma unroll
        for (int j = 0; j < 4; j++) {
          int r = wr + mi * 16 + fq * 4 + j;
          int p = base + r;
          if (p < count2) {
            int col = wc + ni * 16 + fr;
            h2c[(size_t)p * 64 + col] = f2bf(fmaxf(acc[mi][ni][j], 0.f));
          }
        }
  }
}

// ---------------- conv3 via MFMA + fused relu/masked-pool ----------------
#define S3 72    // A/B LDS row stride shorts (144B = 9*16B)
#define SH3 132  // h3 dump row stride shorts
__global__ __launch_bounds__(256) void k_conv3m(
    const unsigned short* __restrict__ h2c,   // [CAP2][64] bf16
    const unsigned short* __restrict__ w3b,   // [27][128][64] bf16
    const int* __restrict__ idx2,
    const int* __restrict__ list2, const int* __restrict__ counter2,
    float* __restrict__ pooled) {             // [16][128] fp32 (global atomic)
  __shared__ __align__(16) unsigned short As[64 * S3];    // 9216 B
  __shared__ __align__(16) unsigned short Bs[128 * S3];   // 18432 B
  __shared__ float pools[4096];                           // [2][16][128] 16 KB
  __shared__ int meta[64];
  __shared__ int posb[64];
  int tid = threadIdx.x;
  int lane = tid & 63, wid = tid >> 6;
  int fr = lane & 15, fq = lane >> 4;
  int wr = (wid >> 1) * 32, wc = (wid & 1) * 64;
  for (int j = tid; j < 4096; j += 256) pools[j] = 0.f;
  int count2 = min(*counter2, CAP2);
  int nchunk = (count2 + 63) >> 6;
  int spos = tid >> 2, sq = tid & 3;   // A staging: 4 threads/row, 32B each
  int boc = tid >> 1, bh = tid & 1;    // B staging: 2 threads/row, 64B each
  for (int ch = blockIdx.x; ch < nchunk; ch += gridDim.x) {
    __syncthreads();
    if (tid < 64) {
      int p = ch * 64 + tid;
      int m = (p < count2) ? list2[p] : -1;
      meta[tid] = m;
      posb[tid] = (m >= 0) ? m / (TD * HD * WD) : 0;
    }
    __syncthreads();
    int mpos = meta[spos];
    int b_ = 0, od = 0, oh = 0, ow = 0;
    if (mpos >= 0) {
      ow = mpos % WD; int r = mpos / WD;
      oh = r % HD; r /= HD;
      od = r % TD; b_ = r / TD;
    }
    f32x4 acc[2][4];
    #pragma unroll
    for (int i = 0; i < 2; i++)
      #pragma unroll
      for (int j = 0; j < 4; j++) acc[i][j] = (f32x4){0.f, 0.f, 0.f, 0.f};
    for (int tap = 0; tap < 27; tap++) {
      int dt = tap / 9 - 1, dh = (tap / 3) % 3 - 1, dw = tap % 3 - 1;
      __syncthreads();
      {
        int row = -1;
        if (mpos >= 0) {
          int t = od + dt, h = oh + dh, w = ow + dw;
          if ((unsigned)t < TD && (unsigned)h < HD && (unsigned)w < WD)
            row = idx2[((b_ * TD + t) * HD + h) * WD + w];
        }
        int4 v0 = {0, 0, 0, 0}, v1 = {0, 0, 0, 0};
        if (row >= 0) {
          const unsigned short* src = h2c + (size_t)row * 64 + sq * 16;
          v0 = *(const int4*)(src);
          v1 = *(const int4*)(src + 8);
        }
        *(int4*)(As + spos * S3 + sq * 16) = v0;
        *(int4*)(As + spos * S3 + sq * 16 + 8) = v1;
        const unsigned short* wsrc = w3b + ((size_t)tap * 128 + boc) * 64 + bh * 32;
        unsigned short* wdst = Bs + boc * S3 + bh * 32;
        *(int4*)(wdst) = *(const int4*)(wsrc);
        *(int4*)(wdst + 8) = *(const int4*)(wsrc + 8);
        *(int4*)(wdst + 16) = *(const int4*)(wsrc + 16);
        *(int4*)(wdst + 24) = *(const int4*)(wsrc + 24);
      }
      __syncthreads();
      const unsigned short* ap = As + (wr + fr) * S3 + fq * 8;
      const unsigned short* bp = Bs + (wc + fr) * S3 + fq * 8;
      #pragma unroll
      for (int kk = 0; kk < 2; kk++) {
        bf16x8 a0 = *(const bf16x8*)(ap + kk * 32);
        bf16x8 a1 = *(const bf16x8*)(ap + 16 * S3 + kk * 32);
        #pragma unroll
        for (int ni = 0; ni < 4; ni++) {
          bf16x8 b = *(const bf16x8*)(bp + ni * 16 * S3 + kk * 32);
          acc[0][ni] = __builtin_amdgcn_mfma_f32_16x16x32_bf16(a0, b, acc[0][ni], 0, 0, 0);
          acc[1][ni] = __builtin_amdgcn_mfma_f32_16x16x32_bf16(a1, b, acc[1][ni], 0, 0, 0);
        }
      }
    }
    // dump relu(h3) into Bs region as bf16, then pool per-b
    __syncthreads();
    unsigned short* h3 = Bs;
    #pragma unroll
    for (int mi = 0; mi < 2; mi++)
      #pragma unroll
      for (int ni = 0; ni < 4; ni++)
        #pragma unroll
        for (int j = 0; j < 4; j++) {
          int r = wr + mi * 16 + fq * 4 + j;
          int col = wc + ni * 16 + fr;
          h3[r * SH3 + col] = f2bf(fmaxf(acc[mi][ni][j], 0.f));
        }
    __syncthreads();
    {
      int oc = tid & 127, half = tid >> 7;
      int pb = half * 2048 + oc;
      for (int r = half * 32; r < half * 32 + 32; r++) {
        float v = bf2f(h3[r * SH3 + oc]);
        pools[pb + posb[r] * 128] += v;
      }
    }
  }
  __syncthreads();
  for (int j = tid; j < 2048; j += 256)
    atomicAdd(&pooled[j], pools[j] + pools[j + 2048]);
}

// ---------------- final: divide, linear, relu, softmax ----------------
__global__ void k_final(const float* __restrict__ pooled, const float* __restrict__ cnt,
                        const float* __restrict__ wl, const float* __restrict__ bl,
                        float* __restrict__ out) {
  __shared__ float pr[128];
  __shared__ float lg[10];
  int b = blockIdx.x;
  int tid = threadIdx.x;
  float c = fmaxf(cnt[b], 1.0f);
  pr[tid] = pooled[b * 128 + tid] / c;
  __syncthreads();
  if (tid < 10) {
    float acc = bl[tid];
    for (int j = 0; j < 128; j++) acc += pr[j] * wl[tid * 128 + j];
    lg[tid] = fmaxf(acc, 0.f);
  }
  __syncthreads();
  if (tid == 0) {
    float mx = lg[0];
    for (int k = 1; k < 10; k++) mx = fmaxf(mx, lg[k]);
    float se = 0.f;
    for (int k = 0; k < 10; k++) se += expf(lg[k] - mx);
    for (int k = 0; k < 10; k++) out[b * 10 + k] = expf(lg[k] - mx) / se;
  }
}

extern "C" void kernel_launch(void* const* d_in, const int* in_sizes, int n_in,
                              void* d_out, int out_size, void* d_ws, size_t ws_size,
                              hipStream_t stream) {
  const float* x  = (const float*)d_in[0];
  const float* w1 = (const float*)d_in[1];
  const float* w2 = (const float*)d_in[2];
  const float* w3 = (const float*)d_in[3];
  const float* wl = (const float*)d_in[4];
  const float* bl = (const float*)d_in[5];
  float* out = (float*)d_out;

  float* ws = (float*)d_ws;
  int* counter1 = (int*)(ws + 0);
  int* counter2 = (int*)(ws + 1);
  float* cnt = ws + 16;             // 16 floats
  float* pooled = ws + 32;          // 2048 floats
  size_t off = 32 + 2048;
  int* idx1 = (int*)(ws + off); off += NP1;
  int* list1 = (int*)(ws + off); off += CAP1;
  unsigned short* h1c = (unsigned short*)(ws + off); off += (size_t)CAP1 * 16;
  int* idx2 = (int*)(ws + off); off += NP2;
  int* list2 = (int*)(ws + off); off += CAP2;
  unsigned short* h2c = (unsigned short*)(ws + off); off += (size_t)CAP2 * 32;
  unsigned short* w2b = (unsigned short*)(ws + off); off += 128000;
  unsigned short* w3b = (unsigned short*)(ws + off); off += 110592;

  hipMemsetAsync(d_ws, 0, 8448, stream);  // counters + cnt + pooled

  k_tw2b<<<(256000 + 255) / 256, 256, 0, stream>>>(w2, w2b);
  k_tw3b<<<(221184 + 255) / 256, 256, 0, stream>>>(w3, w3b);
  k_mask1<<<(NP1 + 255) / 256, 256, 0, stream>>>(x, idx1, list1, counter1);
  k_conv1<<<2048, 256, 0, stream>>>(x, w1, list1, counter1, h1c);
  k_mask2<<<(NP2 + 255) / 256, 256, 0, stream>>>(idx1, idx2, list2, counter2, cnt);
  k_conv2m<<<1024, 256, 0, stream>>>(h1c, w2b, idx1, list2, counter2, h2c);
  k_conv3m<<<768, 256, 0, stream>>>(h2c, w3b, idx2, list2, counter2, pooled);
  k_final<<<16, 128, 0, stream>>>(pooled, cnt, wl, bl, out);
}

// Round 3
// 939.640 us; speedup vs baseline: 2.8662x; 1.5825x over previous
//
#include <hip/hip_runtime.h>

#define BB 16
#define TT 128
#define HH 34
#define WW 34
#define HWSZ (HH*WW)                 // 1156
#define NP1 (BB*TT*HH*WW)            // 2367488
#define TD 64
#define HD 17
#define WD 17
#define NP2 (BB*TD*HD*WD)            // 295936
#define CAP1 262144
#define CAP2 131072

typedef __attribute__((ext_vector_type(8))) short bf16x8;
typedef __attribute__((ext_vector_type(4))) float f32x4;

__device__ inline unsigned short f2bf(float f) {
  unsigned u = __float_as_uint(f);
  unsigned r = (u + 0x7fff + ((u >> 16) & 1)) >> 16;
  return (unsigned short)r;
}
__device__ inline float bf2f(unsigned short s) {
  return __uint_as_float((unsigned)s << 16);
}

// ---------------- mask1: active input positions (b,t,h,w) ----------------
__global__ void k_mask1(const float* __restrict__ x, int* __restrict__ idx1,
                        int* __restrict__ list1, int* __restrict__ counter1) {
  int i = blockIdx.x * blockDim.x + threadIdx.x;
  if (i >= NP1) return;
  int hw = i % HWSZ;
  int bt = i / HWSZ;
  const float* px = x + (size_t)bt * 2 * HWSZ + hw;
  float a = fabsf(px[0]) + fabsf(px[HWSZ]);
  bool act = a > 0.0f;
  unsigned long long m = __ballot(act);
  int lane = threadIdx.x & 63;
  int cntw = __popcll(m);
  int base = 0;
  if (lane == 0 && cntw) base = atomicAdd(counter1, cntw);
  base = __shfl(base, 0);
  if (act) {
    int pos = base + __popcll(m & ((1ull << lane) - 1ull));
    if (pos < CAP1) { idx1[i] = pos; list1[pos] = i; }
    else idx1[i] = -1;
  } else {
    idx1[i] = -1;
  }
}

// ---------------- mask2: pooled mask + count ----------------
__global__ void k_mask2(const int* __restrict__ idx1, int* __restrict__ idx2,
                        int* __restrict__ list2, int* __restrict__ counter2,
                        float* __restrict__ cnt) {
  int i = blockIdx.x * blockDim.x + threadIdx.x;
  if (i >= NP2) return;
  int ow = i % WD; int r = i / WD;
  int oh = r % HD; r /= HD;
  int od = r % TD; int b = r / TD;
  bool act = false;
  for (int dt = 0; dt < 2; dt++)
    for (int dh = 0; dh < 2; dh++)
      for (int dw = 0; dw < 2; dw++) {
        int t = od * 2 + dt, h = oh * 2 + dh, w = ow * 2 + dw;
        int lin = ((b * TT + t) * HH + h) * WW + w;
        if (idx1[lin] >= 0) act = true;
      }
  unsigned long long m = __ballot(act);
  int lane = threadIdx.x & 63;
  int cntw = __popcll(m);
  int base = 0;
  if (lane == 0 && cntw) {
    base = atomicAdd(counter2, cntw);
    atomicAdd(&cnt[b], (float)cntw);
  }
  base = __shfl(base, 0);
  if (act) {
    int pos = base + __popcll(m & ((1ull << lane) - 1ull));
    if (pos < CAP2) { idx2[i] = pos; list2[pos] = i; }
    else idx2[i] = -1;
  } else {
    idx2[i] = -1;
  }
}

// ---------------- conv1: slab-staged LDS + bitmap tap-skipping ----------------
// block = (b, group of 4 output t-slabs). Inputs t0-2..t0+5 staged bf16 in LDS.
__global__ __launch_bounds__(256) void k_conv1s(
    const float* __restrict__ x, const float* __restrict__ w1,
    const int* __restrict__ idx1, unsigned short* __restrict__ h1c) {
  __shared__ unsigned short xs[8 * 2 * 1156];        // 36992 B, [it][c][hw] bf16
  __shared__ unsigned long long bits[8][34];         // 2176 B, bit (w+2) of row h
  __shared__ unsigned short w1s[8000];               // 16000 B bf16
  __shared__ unsigned int plist[4 * 1156];           // 18496 B
  __shared__ int pcnt;
  int tid = threadIdx.x;
  int b = blockIdx.x >> 5;
  int t0 = (blockIdx.x & 31) * 4;
  for (int j = tid; j < 8000; j += 256) w1s[j] = f2bf(w1[j]);
  {
    unsigned long long* bf = &bits[0][0];
    for (int j = tid; j < 272; j += 256) bf[j] = 0ull;
  }
  if (tid == 0) pcnt = 0;
  for (int j = tid; j < 8 * 2 * 1156; j += 256) {
    int it = j / 2312; int r = j - it * 2312;
    int t = t0 - 2 + it;
    float v = 0.f;
    if ((unsigned)t < TT) v = x[((size_t)(b * TT + t)) * 2312 + r];
    xs[j] = f2bf(v);
  }
  __syncthreads();
  // bitmap + output list from idx1 (exact consistency with global compaction)
  for (int j = tid; j < 8 * 1156; j += 256) {
    int it = j / 1156, hw = j - it * 1156;
    int t = t0 - 2 + it;
    int p = -1;
    if ((unsigned)t < TT) p = idx1[(size_t)(b * TT + t) * HWSZ + hw];
    if (p >= 0) {
      int h2 = hw / 34, w2 = hw - h2 * 34;
      unsigned bitpos = w2 + 2;
      unsigned* wp = (unsigned*)&bits[it][h2];
      atomicOr(&wp[bitpos >> 5], 1u << (bitpos & 31));
      if (it >= 2 && it < 6) {
        int s = atomicAdd(&pcnt, 1);
        plist[s] = ((unsigned)p << 13) | ((unsigned)(it - 2) << 11) | (unsigned)hw;
      }
    }
  }
  __syncthreads();
  int n = pcnt;
  int lane = tid & 63, wid = tid >> 6;
  int oc = lane & 31, c = lane >> 5;
  for (int li = wid; li < n; li += 4) {
    unsigned e = plist[li];
    int hw = e & 0x7ff;
    int g = (e >> 11) & 3;
    int p = e >> 13;
    int h_ = hw / 34, w_ = hw - h_ * 34;
    float acc = 0.f;
    for (int kt = 0; kt < 5; kt++) {
      int it2 = g + kt;
      const unsigned short* xc = &xs[(it2 * 2 + c) * 1156];
      #pragma unroll
      for (int kh = 0; kh < 5; kh++) {
        int h2 = h_ + kh - 2;
        if ((unsigned)h2 >= 34) continue;
        unsigned m5 = (unsigned)(bits[it2][h2] >> w_) & 31u;
        while (m5) {
          int kw = __ffs(m5) - 1;
          m5 &= m5 - 1;
          int w2 = w_ + kw - 2;
          int tap = (kt * 5 + kh) * 5 + kw;
          acc += bf2f(xc[h2 * 34 + w2]) * bf2f(w1s[(oc * 2 + c) * 125 + tap]);
        }
      }
    }
    float other = __shfl_down(acc, 32);
    if (lane < 32) h1c[(size_t)p * 32 + oc] = f2bf(acc + other);
  }
}

// ---------------- weight transposes to bf16 [tap][oc][c] ----------------
__global__ void k_tw2b(const float* __restrict__ w2, unsigned short* __restrict__ w2b) {
  int i = blockIdx.x * blockDim.x + threadIdx.x;
  if (i >= 125 * 64 * 32) return;
  int c = i & 31; int r = i >> 5;
  int oc = r & 63; int tap = r >> 6;
  w2b[i] = f2bf(w2[((size_t)oc * 32 + c) * 125 + tap]);
}
__global__ void k_tw3b(const float* __restrict__ w3, unsigned short* __restrict__ w3b) {
  int i = blockIdx.x * blockDim.x + threadIdx.x;
  if (i >= 27 * 128 * 64) return;
  int c = i & 63; int r = i >> 6;
  int oc = r & 127; int tap = r >> 7;
  w3b[i] = f2bf(w3[((size_t)oc * 64 + c) * 27 + tap]);
}

// ---------------- conv2 MFMA: rows precomputed + single-barrier dbuf pipeline ----
#define S2 40
__global__ __launch_bounds__(256) void k_conv2m(
    const unsigned short* __restrict__ h1c,   // [CAP1][32] bf16
    const unsigned short* __restrict__ w2b,   // [125][64][32] bf16
    const int* __restrict__ idx1,
    const int* __restrict__ list2, const int* __restrict__ counter2,
    unsigned short* __restrict__ h2c) {       // [CAP2][64] bf16
  __shared__ __align__(16) unsigned short As[2][64 * S2];
  __shared__ __align__(16) unsigned short Bs[2][64 * S2];
  __shared__ int rowsL[125 * 64];             // 32000 B
  __shared__ int4 mc[64];
  int tid = threadIdx.x;
  int lane = tid & 63, wid = tid >> 6;
  int fr = lane & 15, fq = lane >> 4;
  int wr = (wid >> 1) * 32, wc = (wid & 1) * 32;
  int count2 = min(*counter2, CAP2);
  int nchunk = (count2 + 63) >> 6;
  int spos = tid >> 2, sq = tid & 3;
  for (int ch = blockIdx.x; ch < nchunk; ch += gridDim.x) {
    __syncthreads();
    if (tid < 64) {
      int p = ch * 64 + tid;
      int m = (p < count2) ? list2[p] : -1;
      int4 q; q.x = -1; q.y = 0; q.z = 0; q.w = 0;
      if (m >= 0) {
        int ow = m % WD; int r = m / WD;
        int oh = r % HD; r /= HD;
        q.x = r / TD; q.y = r % TD; q.z = oh; q.w = ow;
      }
      mc[tid] = q;
    }
    __syncthreads();
    for (int j = tid; j < 8000; j += 256) {
      int tap = j >> 6, pos = j & 63;
      int4 q = mc[pos];
      int row = -1;
      if (q.x >= 0) {
        int kt = tap / 25, r2 = tap - kt * 25;
        int kh = r2 / 5, kw = r2 - kh * 5;
        int t = q.y * 2 + kt - 2, h = q.z * 2 + kh - 2, w = q.w * 2 + kw - 2;
        if ((unsigned)t < TT && (unsigned)h < HH && (unsigned)w < WW)
          row = idx1[((q.x * TT + t) * HH + h) * WW + w];
      }
      rowsL[j] = row;
    }
    __syncthreads();
    f32x4 acc[2][2];
    #pragma unroll
    for (int i = 0; i < 2; i++)
      #pragma unroll
      for (int j = 0; j < 2; j++) acc[i][j] = (f32x4){0.f, 0.f, 0.f, 0.f};
    // prefetch tap 0
    int4 rA = {0, 0, 0, 0};
    {
      int row = rowsL[spos];
      if (row >= 0) rA = *(const int4*)(h1c + (size_t)row * 32 + sq * 8);
    }
    int4 rB = *(const int4*)(w2b + (size_t)spos * 32 + sq * 8);
    for (int tap = 0; tap < 125; tap++) {
      int bsel = tap & 1;
      *(int4*)(&As[bsel][spos * S2 + sq * 8]) = rA;
      *(int4*)(&Bs[bsel][spos * S2 + sq * 8]) = rB;
      if (tap < 124) {
        int row = rowsL[(tap + 1) * 64 + spos];
        int4 v = {0, 0, 0, 0};
        if (row >= 0) v = *(const int4*)(h1c + (size_t)row * 32 + sq * 8);
        rA = v;
        rB = *(const int4*)(w2b + ((size_t)(tap + 1) * 64 + spos) * 32 + sq * 8);
      }
      __syncthreads();
      const unsigned short* ap = &As[bsel][(wr + fr) * S2 + fq * 8];
      const unsigned short* bp = &Bs[bsel][(wc + fr) * S2 + fq * 8];
      bf16x8 a0 = *(const bf16x8*)ap;
      bf16x8 a1 = *(const bf16x8*)(ap + 16 * S2);
      bf16x8 b0 = *(const bf16x8*)bp;
      bf16x8 b1 = *(const bf16x8*)(bp + 16 * S2);
      acc[0][0] = __builtin_amdgcn_mfma_f32_16x16x32_bf16(a0, b0, acc[0][0], 0, 0, 0);
      acc[0][1] = __builtin_amdgcn_mfma_f32_16x16x32_bf16(a0, b1, acc[0][1], 0, 0, 0);
      acc[1][0] = __builtin_amdgcn_mfma_f32_16x16x32_bf16(a1, b0, acc[1][0], 0, 0, 0);
      acc[1][1] = __builtin_amdgcn_mfma_f32_16x16x32_bf16(a1, b1, acc[1][1], 0, 0, 0);
    }
    int base = ch * 64;
    #pragma unroll
    for (int mi = 0; mi < 2; mi++)
      #pragma unroll
      for (int ni = 0; ni < 2; ni++)
        #pragma unroll
        for (int j = 0; j < 4; j++) {
          int r = wr + mi * 16 + fq * 4 + j;
          int p = base + r;
          if (p < count2) {
            int col = wc + ni * 16 + fr;
            h2c[(size_t)p * 64 + col] = f2bf(fmaxf(acc[mi][ni][j], 0.f));
          }
        }
  }
}

// ---------------- conv3 MFMA + fused relu/masked-pool, pipelined ----------------
#define S3 72
#define SH3 132
__global__ __launch_bounds__(256) void k_conv3m(
    const unsigned short* __restrict__ h2c,   // [CAP2][64] bf16
    const unsigned short* __restrict__ w3b,   // [27][128][64] bf16
    const int* __restrict__ idx2,
    const int* __restrict__ list2, const int* __restrict__ counter2,
    float* __restrict__ pooled) {             // [16][128] fp32 (global atomic)
  __shared__ __align__(16) unsigned short As[2][64 * S3];    // 18432 B
  __shared__ __align__(16) unsigned short Bs[2][128 * S3];   // 36864 B
  __shared__ float pools[2048];                              // 8192 B
  __shared__ int rowsL[27 * 64];                             // 6912 B
  __shared__ int4 mc[64];
  __shared__ int posb[64];
  int tid = threadIdx.x;
  int lane = tid & 63, wid = tid >> 6;
  int fr = lane & 15, fq = lane >> 4;
  int wr = (wid >> 1) * 32, wc = (wid & 1) * 64;
  for (int j = tid; j < 2048; j += 256) pools[j] = 0.f;
  int count2 = min(*counter2, CAP2);
  int nchunk = (count2 + 63) >> 6;
  int spos = tid >> 2, sq = tid & 3;
  int boc = tid >> 1, bh = tid & 1;
  for (int ch = blockIdx.x; ch < nchunk; ch += gridDim.x) {
    __syncthreads();
    if (tid < 64) {
      int p = ch * 64 + tid;
      int m = (p < count2) ? list2[p] : -1;
      int4 q; q.x = -1; q.y = 0; q.z = 0; q.w = 0;
      if (m >= 0) {
        int ow = m % WD; int r = m / WD;
        int oh = r % HD; r /= HD;
        q.x = r / TD; q.y = r % TD; q.z = oh; q.w = ow;
      }
      mc[tid] = q;
      posb[tid] = (q.x >= 0) ? q.x : 0;
    }
    __syncthreads();
    for (int j = tid; j < 27 * 64; j += 256) {
      int tap = j >> 6, pos = j & 63;
      int4 q = mc[pos];
      int row = -1;
      if (q.x >= 0) {
        int dt = tap / 9 - 1, dh = (tap / 3) % 3 - 1, dw = tap % 3 - 1;
        int t = q.y + dt, h = q.z + dh, w = q.w + dw;
        if ((unsigned)t < TD && (unsigned)h < HD && (unsigned)w < WD)
          row = idx2[((q.x * TD + t) * HD + h) * WD + w];
      }
      rowsL[j] = row;
    }
    __syncthreads();
    f32x4 acc[2][4];
    #pragma unroll
    for (int i = 0; i < 2; i++)
      #pragma unroll
      for (int j = 0; j < 4; j++) acc[i][j] = (f32x4){0.f, 0.f, 0.f, 0.f};
    // prefetch tap 0
    int4 rA0 = {0, 0, 0, 0}, rA1 = {0, 0, 0, 0};
    {
      int row = rowsL[spos];
      if (row >= 0) {
        const unsigned short* s = h2c + (size_t)row * 64 + sq * 16;
        rA0 = *(const int4*)s;
        rA1 = *(const int4*)(s + 8);
      }
    }
    int4 rB0, rB1, rB2, rB3;
    {
      const unsigned short* wsrc = w3b + (size_t)boc * 64 + bh * 32;
      rB0 = *(const int4*)(wsrc);
      rB1 = *(const int4*)(wsrc + 8);
      rB2 = *(const int4*)(wsrc + 16);
      rB3 = *(const int4*)(wsrc + 24);
    }
    for (int tap = 0; tap < 27; tap++) {
      int bsel = tap & 1;
      {
        unsigned short* ad = &As[bsel][spos * S3 + sq * 16];
        *(int4*)(ad) = rA0;
        *(int4*)(ad + 8) = rA1;
        unsigned short* bd = &Bs[bsel][boc * S3 + bh * 32];
        *(int4*)(bd) = rB0;
        *(int4*)(bd + 8) = rB1;
        *(int4*)(bd + 16) = rB2;
        *(int4*)(bd + 24) = rB3;
      }
      if (tap < 26) {
        int row = rowsL[(tap + 1) * 64 + spos];
        int4 v0 = {0, 0, 0, 0}, v1 = {0, 0, 0, 0};
        if (row >= 0) {
          const unsigned short* s = h2c + (size_t)row * 64 + sq * 16;
          v0 = *(const int4*)s;
          v1 = *(const int4*)(s + 8);
        }
        rA0 = v0; rA1 = v1;
        const unsigned short* wsrc = w3b + ((size_t)(tap + 1) * 128 + boc) * 64 + bh * 32;
        rB0 = *(const int4*)(wsrc);
        rB1 = *(const int4*)(wsrc + 8);
        rB2 = *(const int4*)(wsrc + 16);
        rB3 = *(const int4*)(wsrc + 24);
      }
      __syncthreads();
      const unsigned short* ap = &As[bsel][(wr + fr) * S3 + fq * 8];
      const unsigned short* bp = &Bs[bsel][(wc + fr) * S3 + fq * 8];
      #pragma unroll
      for (int kk = 0; kk < 2; kk++) {
        bf16x8 a0 = *(const bf16x8*)(ap + kk * 32);
        bf16x8 a1 = *(const bf16x8*)(ap + 16 * S3 + kk * 32);
        #pragma unroll
        for (int ni = 0; ni < 4; ni++) {
          bf16x8 bfrag = *(const bf16x8*)(bp + ni * 16 * S3 + kk * 32);
          acc[0][ni] = __builtin_amdgcn_mfma_f32_16x16x32_bf16(a0, bfrag, acc[0][ni], 0, 0, 0);
          acc[1][ni] = __builtin_amdgcn_mfma_f32_16x16x32_bf16(a1, bfrag, acc[1][ni], 0, 0, 0);
        }
      }
    }
    // dump relu(h3) into As (both buffers, contiguous), then pool per-b
    __syncthreads();
    unsigned short* h3 = &As[0][0];   // needs 64*SH3=8448 shorts <= 9216
    #pragma unroll
    for (int mi = 0; mi < 2; mi++)
      #pragma unroll
      for (int ni = 0; ni < 4; ni++)
        #pragma unroll
        for (int j = 0; j < 4; j++) {
          int r = wr + mi * 16 + fq * 4 + j;
          int col = wc + ni * 16 + fr;
          h3[r * SH3 + col] = f2bf(fmaxf(acc[mi][ni][j], 0.f));
        }
    __syncthreads();
    if (tid < 128) {
      for (int r = 0; r < 64; r++)
        pools[posb[r] * 128 + tid] += bf2f(h3[r * SH3 + tid]);
    }
  }
  __syncthreads();
  for (int j = tid; j < 2048; j += 256)
    atomicAdd(&pooled[j], pools[j]);
}

// ---------------- final: divide, linear, relu, softmax ----------------
__global__ void k_final(const float* __restrict__ pooled, const float* __restrict__ cnt,
                        const float* __restrict__ wl, const float* __restrict__ bl,
                        float* __restrict__ out) {
  __shared__ float pr[128];
  __shared__ float lg[10];
  int b = blockIdx.x;
  int tid = threadIdx.x;
  float c = fmaxf(cnt[b], 1.0f);
  pr[tid] = pooled[b * 128 + tid] / c;
  __syncthreads();
  if (tid < 10) {
    float acc = bl[tid];
    for (int j = 0; j < 128; j++) acc += pr[j] * wl[tid * 128 + j];
    lg[tid] = fmaxf(acc, 0.f);
  }
  __syncthreads();
  if (tid == 0) {
    float mx = lg[0];
    for (int k = 1; k < 10; k++) mx = fmaxf(mx, lg[k]);
    float se = 0.f;
    for (int k = 0; k < 10; k++) se += expf(lg[k] - mx);
    for (int k = 0; k < 10; k++) out[b * 10 + k] = expf(lg[k] - mx) / se;
  }
}

extern "C" void kernel_launch(void* const* d_in, const int* in_sizes, int n_in,
                              void* d_out, int out_size, void* d_ws, size_t ws_size,
                              hipStream_t stream) {
  const float* x  = (const float*)d_in[0];
  const float* w1 = (const float*)d_in[1];
  const float* w2 = (const float*)d_in[2];
  const float* w3 = (const float*)d_in[3];
  const float* wl = (const float*)d_in[4];
  const float* bl = (const float*)d_in[5];
  float* out = (float*)d_out;

  float* ws = (float*)d_ws;
  int* counter1 = (int*)(ws + 0);
  int* counter2 = (int*)(ws + 1);
  float* cnt = ws + 16;             // 16 floats
  float* pooled = ws + 32;          // 2048 floats
  size_t off = 32 + 2048;
  int* idx1 = (int*)(ws + off); off += NP1;
  int* list1 = (int*)(ws + off); off += CAP1;
  unsigned short* h1c = (unsigned short*)(ws + off); off += (size_t)CAP1 * 16;
  int* idx2 = (int*)(ws + off); off += NP2;
  int* list2 = (int*)(ws + off); off += CAP2;
  unsigned short* h2c = (unsigned short*)(ws + off); off += (size_t)CAP2 * 32;
  unsigned short* w2b = (unsigned short*)(ws + off); off += 128000;
  unsigned short* w3b = (unsigned short*)(ws + off); off += 110592;

  hipMemsetAsync(d_ws, 0, 8448, stream);  // counters + cnt + pooled

  k_tw2b<<<(256000 + 255) / 256, 256, 0, stream>>>(w2, w2b);
  k_tw3b<<<(221184 + 255) / 256, 256, 0, stream>>>(w3, w3b);
  k_mask1<<<(NP1 + 255) / 256, 256, 0, stream>>>(x, idx1, list1, counter1);
  k_conv1s<<<512, 256, 0, stream>>>(x, w1, idx1, h1c);
  k_mask2<<<(NP2 + 255) / 256, 256, 0, stream>>>(idx1, idx2, list2, counter2, cnt);
  k_conv2m<<<1024, 256, 0, stream>>>(h1c, w2b, idx1, list2, counter2, h2c);
  k_conv3m<<<768, 256, 0, stream>>>(h2c, w3b, idx2, list2, counter2, pooled);
  k_final<<<16, 128, 0, stream>>>(pooled, cnt, wl, bl, out);
}

// Round 4
// 549.936 us; speedup vs baseline: 4.8973x; 1.7086x over previous
//
#include <hip/hip_runtime.h>

#define BB 16
#define TT 128
#define HH 34
#define WW 34
#define HWSZ (HH*WW)                 // 1156
#define NP1 (BB*TT*HH*WW)            // 2367488
#define TD 64
#define HD 17
#define WD 17
#define NP2 (BB*TD*HD*WD)            // 295936
#define NW1 (NP1/64)                 // 36992
#define NW2 (NP2/64)                 // 4624
#define CAP1 262144
#define CAP2 131072

typedef __attribute__((ext_vector_type(8))) short bf16x8;
typedef __attribute__((ext_vector_type(4))) float f32x4;

__device__ inline unsigned short f2bf(float f) {
  unsigned u = __float_as_uint(f);
  unsigned r = (u + 0x7fff + ((u >> 16) & 1)) >> 16;
  return (unsigned short)r;
}
__device__ inline float bf2f(unsigned short s) {
  return __uint_as_float((unsigned)s << 16);
}

// ---------------- ballot1: per-wave activity bitmap of input positions ----------------
__global__ void k_ballot1(const float* __restrict__ x, unsigned long long* __restrict__ b1) {
  int i = blockIdx.x * 256 + threadIdx.x;
  int hw = i % HWSZ;
  int bt = i / HWSZ;
  const float* px = x + (size_t)bt * 2 * HWSZ + hw;
  bool act = (fabsf(px[0]) + fabsf(px[HWSZ])) > 0.0f;
  unsigned long long m = __ballot(act);
  if ((threadIdx.x & 63) == 0) b1[i >> 6] = m;
}

// ---------------- ballot2: pooled activity bitmap from b1 ----------------
__global__ void k_ballot2(const unsigned long long* __restrict__ b1,
                          unsigned long long* __restrict__ b2) {
  int i = blockIdx.x * 256 + threadIdx.x;
  if (i >= NP2) return;
  int ow = i % WD; int r = i / WD;
  int oh = r % HD; r /= HD;
  int od = r % TD; int b = r / TD;
  bool act = false;
  for (int dt = 0; dt < 2; dt++)
    for (int dh = 0; dh < 2; dh++)
      for (int dw = 0; dw < 2; dw++) {
        int t = od * 2 + dt, h = oh * 2 + dh, w = ow * 2 + dw;
        int lin = ((b * TT + t) * HH + h) * WW + w;
        if ((b1[lin >> 6] >> (lin & 63)) & 1ull) act = true;
      }
  unsigned long long m = __ballot(act);
  if ((threadIdx.x & 63) == 0) b2[i >> 6] = m;
}

// ---------------- scan: exclusive prefix of wave popcounts (no atomics) ----------------
__global__ __launch_bounds__(1024) void k_scan(
    const unsigned long long* __restrict__ b1, const unsigned long long* __restrict__ b2,
    int* __restrict__ wb1, int* __restrict__ wb2,
    int* __restrict__ counter1, int* __restrict__ counter2, float* __restrict__ cnt) {
  __shared__ int wsum[16];
  __shared__ int wpre[16];
  __shared__ int tots[2];
  int tid = threadIdx.x, lane = tid & 63, wv = tid >> 6;

  // ---- part 1: b1 (NW1 waves) ----
  const int CH1 = (NW1 + 1023) / 1024;
  int lo = tid * CH1, hi = min(lo + CH1, NW1);
  int s = 0;
  for (int i = lo; i < hi; i++) s += __popcll(b1[i]);
  int sc = s;
  #pragma unroll
  for (int d = 1; d < 64; d <<= 1) { int y = __shfl_up(sc, d); if (lane >= d) sc += y; }
  if (lane == 63) wsum[wv] = sc;
  __syncthreads();
  if (wv == 0 && lane < 16) {
    int v = wsum[lane];
    int p = v;
    #pragma unroll
    for (int d = 1; d < 16; d <<= 1) { int y = __shfl_up(p, d); if (lane >= d) p += y; }
    wpre[lane] = p - v;
    if (lane == 15) tots[0] = p;
  }
  __syncthreads();
  {
    int base = wpre[wv] + (sc - s);
    for (int i = lo; i < hi; i++) { wb1[i] = base; base += __popcll(b1[i]); }
  }
  if (tid == 0) *counter1 = tots[0];
  __syncthreads();

  // ---- part 2: b2 (NW2 waves) ----
  const int CH2 = (NW2 + 1023) / 1024;
  lo = tid * CH2; hi = min(lo + CH2, NW2);
  s = 0;
  for (int i = lo; i < hi; i++) s += __popcll(b2[i]);
  sc = s;
  #pragma unroll
  for (int d = 1; d < 64; d <<= 1) { int y = __shfl_up(sc, d); if (lane >= d) sc += y; }
  if (lane == 63) wsum[wv] = sc;
  __syncthreads();
  if (wv == 0 && lane < 16) {
    int v = wsum[lane];
    int p = v;
    #pragma unroll
    for (int d = 1; d < 16; d <<= 1) { int y = __shfl_up(p, d); if (lane >= d) p += y; }
    wpre[lane] = p - v;
    if (lane == 15) tots[1] = p;
  }
  __syncthreads();
  {
    int base = wpre[wv] + (sc - s);
    for (int i = lo; i < hi; i++) { wb2[i] = base; base += __popcll(b2[i]); }
  }
  if (tid == 0) *counter2 = tots[1];
  __syncthreads();
  // cnt[b]: each batch owns exactly 289 waves of b2
  if (tid < 16) {
    int c0 = wb2[tid * 289];
    int c1 = (tid == 15) ? tots[1] : wb2[(tid + 1) * 289];
    cnt[tid] = (float)(c1 - c0);
  }
}

// ---------------- fill1: idx1 from ballots (deterministic, linear order) ----------------
__global__ void k_fill1(const unsigned long long* __restrict__ b1,
                        const int* __restrict__ wb1, int* __restrict__ idx1) {
  int i = blockIdx.x * 256 + threadIdx.x;
  unsigned long long m = b1[i >> 6];
  int lane = i & 63;
  int p = -1;
  if ((m >> lane) & 1ull) {
    p = wb1[i >> 6] + __popcll(m & ((1ull << lane) - 1ull));
    if (p >= CAP1) p = -1;
  }
  idx1[i] = p;
}

// ---------------- fill2: idx2 + list2 ----------------
__global__ void k_fill2(const unsigned long long* __restrict__ b2,
                        const int* __restrict__ wb2,
                        int* __restrict__ idx2, int* __restrict__ list2) {
  int i = blockIdx.x * 256 + threadIdx.x;
  if (i >= NP2) return;
  unsigned long long m = b2[i >> 6];
  int lane = i & 63;
  int p = -1;
  if ((m >> lane) & 1ull) {
    p = wb2[i >> 6] + __popcll(m & ((1ull << lane) - 1ull));
    if (p < CAP2) list2[p] = i; else p = -1;
  }
  idx2[i] = p;
}

// ---------------- conv1: slab-staged LDS + bitmap tap-skipping ----------------
__global__ __launch_bounds__(256) void k_conv1s(
    const float* __restrict__ x, const float* __restrict__ w1,
    const int* __restrict__ idx1, unsigned short* __restrict__ h1c) {
  __shared__ unsigned short xs[8 * 2 * 1156];        // 36992 B, [it][c][hw] bf16
  __shared__ unsigned long long bits[8][34];         // 2176 B
  __shared__ unsigned short w1s[8000];               // 16000 B bf16
  __shared__ unsigned int plist[4 * 1156];           // 18496 B
  __shared__ int pcnt;
  int tid = threadIdx.x;
  int b = blockIdx.x >> 5;
  int t0 = (blockIdx.x & 31) * 4;
  for (int j = tid; j < 8000; j += 256) w1s[j] = f2bf(w1[j]);
  {
    unsigned long long* bf = &bits[0][0];
    for (int j = tid; j < 272; j += 256) bf[j] = 0ull;
  }
  if (tid == 0) pcnt = 0;
  for (int j = tid; j < 8 * 2 * 1156; j += 256) {
    int it = j / 2312; int r = j - it * 2312;
    int t = t0 - 2 + it;
    float v = 0.f;
    if ((unsigned)t < TT) v = x[((size_t)(b * TT + t)) * 2312 + r];
    xs[j] = f2bf(v);
  }
  __syncthreads();
  for (int j = tid; j < 8 * 1156; j += 256) {
    int it = j / 1156, hw = j - it * 1156;
    int t = t0 - 2 + it;
    int p = -1;
    if ((unsigned)t < TT) p = idx1[(size_t)(b * TT + t) * HWSZ + hw];
    if (p >= 0) {
      int h2 = hw / 34, w2 = hw - h2 * 34;
      unsigned bitpos = w2 + 2;
      unsigned* wp = (unsigned*)&bits[it][h2];
      atomicOr(&wp[bitpos >> 5], 1u << (bitpos & 31));
      if (it >= 2 && it < 6) {
        int s = atomicAdd(&pcnt, 1);
        plist[s] = ((unsigned)p << 13) | ((unsigned)(it - 2) << 11) | (unsigned)hw;
      }
    }
  }
  __syncthreads();
  int n = pcnt;
  int lane = tid & 63, wid = tid >> 6;
  int oc = lane & 31, c = lane >> 5;
  for (int li = wid; li < n; li += 4) {
    unsigned e = plist[li];
    int hw = e & 0x7ff;
    int g = (e >> 11) & 3;
    int p = e >> 13;
    int h_ = hw / 34, w_ = hw - h_ * 34;
    float acc = 0.f;
    for (int kt = 0; kt < 5; kt++) {
      int it2 = g + kt;
      const unsigned short* xc = &xs[(it2 * 2 + c) * 1156];
      #pragma unroll
      for (int kh = 0; kh < 5; kh++) {
        int h2 = h_ + kh - 2;
        if ((unsigned)h2 >= 34) continue;
        unsigned m5 = (unsigned)(bits[it2][h2] >> w_) & 31u;
        while (m5) {
          int kw = __ffs(m5) - 1;
          m5 &= m5 - 1;
          int w2 = w_ + kw - 2;
          int tap = (kt * 5 + kh) * 5 + kw;
          acc += bf2f(xc[h2 * 34 + w2]) * bf2f(w1s[(oc * 2 + c) * 125 + tap]);
        }
      }
    }
    float other = __shfl_down(acc, 32);
    if (lane < 32) h1c[(size_t)p * 32 + oc] = f2bf(acc + other);
  }
}

// ---------------- weight transposes to bf16 [tap][oc][c] ----------------
__global__ void k_tw2b(const float* __restrict__ w2, unsigned short* __restrict__ w2b) {
  int i = blockIdx.x * blockDim.x + threadIdx.x;
  if (i >= 125 * 64 * 32) return;
  int c = i & 31; int r = i >> 5;
  int oc = r & 63; int tap = r >> 6;
  w2b[i] = f2bf(w2[((size_t)oc * 32 + c) * 125 + tap]);
}
__global__ void k_tw3b(const float* __restrict__ w3, unsigned short* __restrict__ w3b) {
  int i = blockIdx.x * blockDim.x + threadIdx.x;
  if (i >= 27 * 128 * 64) return;
  int c = i & 63; int r = i >> 6;
  int oc = r & 127; int tap = r >> 7;
  w3b[i] = f2bf(w3[((size_t)oc * 64 + c) * 27 + tap]);
}

// ---------------- conv2 MFMA: rows precomputed + single-barrier dbuf pipeline ----
#define S2 40
__global__ __launch_bounds__(256) void k_conv2m(
    const unsigned short* __restrict__ h1c,   // [CAP1][32] bf16
    const unsigned short* __restrict__ w2b,   // [125][64][32] bf16
    const int* __restrict__ idx1,
    const int* __restrict__ list2, const int* __restrict__ counter2,
    unsigned short* __restrict__ h2c) {       // [CAP2][64] bf16
  __shared__ __align__(16) unsigned short As[2][64 * S2];
  __shared__ __align__(16) unsigned short Bs[2][64 * S2];
  __shared__ int rowsL[125 * 64];
  __shared__ int4 mc[64];
  int tid = threadIdx.x;
  int lane = tid & 63, wid = tid >> 6;
  int fr = lane & 15, fq = lane >> 4;
  int wr = (wid >> 1) * 32, wc = (wid & 1) * 32;
  int count2 = min(*counter2, CAP2);
  int nchunk = (count2 + 63) >> 6;
  int spos = tid >> 2, sq = tid & 3;
  for (int ch = blockIdx.x; ch < nchunk; ch += gridDim.x) {
    __syncthreads();
    if (tid < 64) {
      int p = ch * 64 + tid;
      int m = (p < count2) ? list2[p] : -1;
      int4 q; q.x = -1; q.y = 0; q.z = 0; q.w = 0;
      if (m >= 0) {
        int ow = m % WD; int r = m / WD;
        int oh = r % HD; r /= HD;
        q.x = r / TD; q.y = r % TD; q.z = oh; q.w = ow;
      }
      mc[tid] = q;
    }
    __syncthreads();
    for (int j = tid; j < 8000; j += 256) {
      int tap = j >> 6, pos = j & 63;
      int4 q = mc[pos];
      int row = -1;
      if (q.x >= 0) {
        int kt = tap / 25, r2 = tap - kt * 25;
        int kh = r2 / 5, kw = r2 - kh * 5;
        int t = q.y * 2 + kt - 2, h = q.z * 2 + kh - 2, w = q.w * 2 + kw - 2;
        if ((unsigned)t < TT && (unsigned)h < HH && (unsigned)w < WW)
          row = idx1[((q.x * TT + t) * HH + h) * WW + w];
      }
      rowsL[j] = row;
    }
    __syncthreads();
    f32x4 acc[2][2];
    #pragma unroll
    for (int i = 0; i < 2; i++)
      #pragma unroll
      for (int j = 0; j < 2; j++) acc[i][j] = (f32x4){0.f, 0.f, 0.f, 0.f};
    int4 rA = {0, 0, 0, 0};
    {
      int row = rowsL[spos];
      if (row >= 0) rA = *(const int4*)(h1c + (size_t)row * 32 + sq * 8);
    }
    int4 rB = *(const int4*)(w2b + (size_t)spos * 32 + sq * 8);
    for (int tap = 0; tap < 125; tap++) {
      int bsel = tap & 1;
      *(int4*)(&As[bsel][spos * S2 + sq * 8]) = rA;
      *(int4*)(&Bs[bsel][spos * S2 + sq * 8]) = rB;
      if (tap < 124) {
        int row = rowsL[(tap + 1) * 64 + spos];
        int4 v = {0, 0, 0, 0};
        if (row >= 0) v = *(const int4*)(h1c + (size_t)row * 32 + sq * 8);
        rA = v;
        rB = *(const int4*)(w2b + ((size_t)(tap + 1) * 64 + spos) * 32 + sq * 8);
      }
      __syncthreads();
      const unsigned short* ap = &As[bsel][(wr + fr) * S2 + fq * 8];
      const unsigned short* bp = &Bs[bsel][(wc + fr) * S2 + fq * 8];
      bf16x8 a0 = *(const bf16x8*)ap;
      bf16x8 a1 = *(const bf16x8*)(ap + 16 * S2);
      bf16x8 b0 = *(const bf16x8*)bp;
      bf16x8 b1 = *(const bf16x8*)(bp + 16 * S2);
      acc[0][0] = __builtin_amdgcn_mfma_f32_16x16x32_bf16(a0, b0, acc[0][0], 0, 0, 0);
      acc[0][1] = __builtin_amdgcn_mfma_f32_16x16x32_bf16(a0, b1, acc[0][1], 0, 0, 0);
      acc[1][0] = __builtin_amdgcn_mfma_f32_16x16x32_bf16(a1, b0, acc[1][0], 0, 0, 0);
      acc[1][1] = __builtin_amdgcn_mfma_f32_16x16x32_bf16(a1, b1, acc[1][1], 0, 0, 0);
    }
    int base = ch * 64;
    #pragma unroll
    for (int mi = 0; mi < 2; mi++)
      #pragma unroll
      for (int ni = 0; ni < 2; ni++)
        #pragma unroll
        for (int j = 0; j < 4; j++) {
          int r = wr + mi * 16 + fq * 4 + j;
          int p = base + r;
          if (p < count2) {
            int col = wc + ni * 16 + fr;
            h2c[(size_t)p * 64 + col] = f2bf(fmaxf(acc[mi][ni][j], 0.f));
          }
        }
  }
}

// ---------------- conv3 MFMA + fused relu/masked-pool, pipelined ----------------
#define S3 72
#define SH3 132
__global__ __launch_bounds__(256) void k_conv3m(
    const unsigned short* __restrict__ h2c,   // [CAP2][64] bf16
    const unsigned short* __restrict__ w3b,   // [27][128][64] bf16
    const int* __restrict__ idx2,
    const int* __restrict__ list2, const int* __restrict__ counter2,
    float* __restrict__ pooled) {             // [16][128] fp32 (global atomic)
  __shared__ __align__(16) unsigned short As[2][64 * S3];
  __shared__ __align__(16) unsigned short Bs[2][128 * S3];
  __shared__ float pools[2048];
  __shared__ int rowsL[27 * 64];
  __shared__ int4 mc[64];
  __shared__ int posb[64];
  int tid = threadIdx.x;
  int lane = tid & 63, wid = tid >> 6;
  int fr = lane & 15, fq = lane >> 4;
  int wr = (wid >> 1) * 32, wc = (wid & 1) * 64;
  for (int j = tid; j < 2048; j += 256) pools[j] = 0.f;
  int count2 = min(*counter2, CAP2);
  int nchunk = (count2 + 63) >> 6;
  int spos = tid >> 2, sq = tid & 3;
  int boc = tid >> 1, bh = tid & 1;
  for (int ch = blockIdx.x; ch < nchunk; ch += gridDim.x) {
    __syncthreads();
    if (tid < 64) {
      int p = ch * 64 + tid;
      int m = (p < count2) ? list2[p] : -1;
      int4 q; q.x = -1; q.y = 0; q.z = 0; q.w = 0;
      if (m >= 0) {
        int ow = m % WD; int r = m / WD;
        int oh = r % HD; r /= HD;
        q.x = r / TD; q.y = r % TD; q.z = oh; q.w = ow;
      }
      mc[tid] = q;
      posb[tid] = (q.x >= 0) ? q.x : 0;
    }
    __syncthreads();
    for (int j = tid; j < 27 * 64; j += 256) {
      int tap = j >> 6, pos = j & 63;
      int4 q = mc[pos];
      int row = -1;
      if (q.x >= 0) {
        int dt = tap / 9 - 1, dh = (tap / 3) % 3 - 1, dw = tap % 3 - 1;
        int t = q.y + dt, h = q.z + dh, w = q.w + dw;
        if ((unsigned)t < TD && (unsigned)h < HD && (unsigned)w < WD)
          row = idx2[((q.x * TD + t) * HD + h) * WD + w];
      }
      rowsL[j] = row;
    }
    __syncthreads();
    f32x4 acc[2][4];
    #pragma unroll
    for (int i = 0; i < 2; i++)
      #pragma unroll
      for (int j = 0; j < 4; j++) acc[i][j] = (f32x4){0.f, 0.f, 0.f, 0.f};
    int4 rA0 = {0, 0, 0, 0}, rA1 = {0, 0, 0, 0};
    {
      int row = rowsL[spos];
      if (row >= 0) {
        const unsigned short* s = h2c + (size_t)row * 64 + sq * 16;
        rA0 = *(const int4*)s;
        rA1 = *(const int4*)(s + 8);
      }
    }
    int4 rB0, rB1, rB2, rB3;
    {
      const unsigned short* wsrc = w3b + (size_t)boc * 64 + bh * 32;
      rB0 = *(const int4*)(wsrc);
      rB1 = *(const int4*)(wsrc + 8);
      rB2 = *(const int4*)(wsrc + 16);
      rB3 = *(const int4*)(wsrc + 24);
    }
    for (int tap = 0; tap < 27; tap++) {
      int bsel = tap & 1;
      {
        unsigned short* ad = &As[bsel][spos * S3 + sq * 16];
        *(int4*)(ad) = rA0;
        *(int4*)(ad + 8) = rA1;
        unsigned short* bd = &Bs[bsel][boc * S3 + bh * 32];
        *(int4*)(bd) = rB0;
        *(int4*)(bd + 8) = rB1;
        *(int4*)(bd + 16) = rB2;
        *(int4*)(bd + 24) = rB3;
      }
      if (tap < 26) {
        int row = rowsL[(tap + 1) * 64 + spos];
        int4 v0 = {0, 0, 0, 0}, v1 = {0, 0, 0, 0};
        if (row >= 0) {
          const unsigned short* s = h2c + (size_t)row * 64 + sq * 16;
          v0 = *(const int4*)s;
          v1 = *(const int4*)(s + 8);
        }
        rA0 = v0; rA1 = v1;
        const unsigned short* wsrc = w3b + ((size_t)(tap + 1) * 128 + boc) * 64 + bh * 32;
        rB0 = *(const int4*)(wsrc);
        rB1 = *(const int4*)(wsrc + 8);
        rB2 = *(const int4*)(wsrc + 16);
        rB3 = *(const int4*)(wsrc + 24);
      }
      __syncthreads();
      const unsigned short* ap = &As[bsel][(wr + fr) * S3 + fq * 8];
      const unsigned short* bp = &Bs[bsel][(wc + fr) * S3 + fq * 8];
      #pragma unroll
      for (int kk = 0; kk < 2; kk++) {
        bf16x8 a0 = *(const bf16x8*)(ap + kk * 32);
        bf16x8 a1 = *(const bf16x8*)(ap + 16 * S3 + kk * 32);
        #pragma unroll
        for (int ni = 0; ni < 4; ni++) {
          bf16x8 bfrag = *(const bf16x8*)(bp + ni * 16 * S3 + kk * 32);
          acc[0][ni] = __builtin_amdgcn_mfma_f32_16x16x32_bf16(a0, bfrag, acc[0][ni], 0, 0, 0);
          acc[1][ni] = __builtin_amdgcn_mfma_f32_16x16x32_bf16(a1, bfrag, acc[1][ni], 0, 0, 0);
        }
      }
    }
    __syncthreads();
    unsigned short* h3 = &As[0][0];
    #pragma unroll
    for (int mi = 0; mi < 2; mi++)
      #pragma unroll
      for (int ni = 0; ni < 4; ni++)
        #pragma unroll
        for (int j = 0; j < 4; j++) {
          int r = wr + mi * 16 + fq * 4 + j;
          int col = wc + ni * 16 + fr;
          h3[r * SH3 + col] = f2bf(fmaxf(acc[mi][ni][j], 0.f));
        }
    __syncthreads();
    if (tid < 128) {
      for (int r = 0; r < 64; r++)
        pools[posb[r] * 128 + tid] += bf2f(h3[r * SH3 + tid]);
    }
  }
  __syncthreads();
  for (int j = tid; j < 2048; j += 256)
    atomicAdd(&pooled[j], pools[j]);
}

// ---------------- final: divide, linear, relu, softmax ----------------
__global__ void k_final(const float* __restrict__ pooled, const float* __restrict__ cnt,
                        const float* __restrict__ wl, const float* __restrict__ bl,
                        float* __restrict__ out) {
  __shared__ float pr[128];
  __shared__ float lg[10];
  int b = blockIdx.x;
  int tid = threadIdx.x;
  float c = fmaxf(cnt[b], 1.0f);
  pr[tid] = pooled[b * 128 + tid] / c;
  __syncthreads();
  if (tid < 10) {
    float acc = bl[tid];
    for (int j = 0; j < 128; j++) acc += pr[j] * wl[tid * 128 + j];
    lg[tid] = fmaxf(acc, 0.f);
  }
  __syncthreads();
  if (tid == 0) {
    float mx = lg[0];
    for (int k = 1; k < 10; k++) mx = fmaxf(mx, lg[k]);
    float se = 0.f;
    for (int k = 0; k < 10; k++) se += expf(lg[k] - mx);
    for (int k = 0; k < 10; k++) out[b * 10 + k] = expf(lg[k] - mx) / se;
  }
}

extern "C" void kernel_launch(void* const* d_in, const int* in_sizes, int n_in,
                              void* d_out, int out_size, void* d_ws, size_t ws_size,
                              hipStream_t stream) {
  const float* x  = (const float*)d_in[0];
  const float* w1 = (const float*)d_in[1];
  const float* w2 = (const float*)d_in[2];
  const float* w3 = (const float*)d_in[3];
  const float* wl = (const float*)d_in[4];
  const float* bl = (const float*)d_in[5];
  float* out = (float*)d_out;

  float* ws = (float*)d_ws;
  int* counter1 = (int*)(ws + 0);
  int* counter2 = (int*)(ws + 1);
  float* cnt = ws + 16;             // 16 floats
  float* pooled = ws + 32;          // 2048 floats
  size_t off = 2080;                // even (8B alignment for u64)
  unsigned long long* b1 = (unsigned long long*)(ws + off); off += NW1 * 2;
  unsigned long long* b2 = (unsigned long long*)(ws + off); off += NW2 * 2;
  int* wb1 = (int*)(ws + off); off += NW1;
  int* wb2 = (int*)(ws + off); off += NW2;
  int* idx1 = (int*)(ws + off); off += NP1;
  unsigned short* h1c = (unsigned short*)(ws + off); off += (size_t)CAP1 * 16;
  int* idx2 = (int*)(ws + off); off += NP2;
  int* list2 = (int*)(ws + off); off += CAP2;
  unsigned short* h2c = (unsigned short*)(ws + off); off += (size_t)CAP2 * 32;
  unsigned short* w2b = (unsigned short*)(ws + off); off += 128000;
  unsigned short* w3b = (unsigned short*)(ws + off); off += 110592;

  hipMemsetAsync(d_ws, 0, 8448, stream);  // counters + cnt + pooled

  k_tw2b<<<(256000 + 255) / 256, 256, 0, stream>>>(w2, w2b);
  k_tw3b<<<(221184 + 255) / 256, 256, 0, stream>>>(w3, w3b);
  k_ballot1<<<NP1 / 256, 256, 0, stream>>>(x, b1);
  k_ballot2<<<(NP2 + 255) / 256, 256, 0, stream>>>(b1, b2);
  k_scan<<<1, 1024, 0, stream>>>(b1, b2, wb1, wb2, counter1, counter2, cnt);
  k_fill1<<<NP1 / 256, 256, 0, stream>>>(b1, wb1, idx1);
  k_fill2<<<(NP2 + 255) / 256, 256, 0, stream>>>(b2, wb2, idx2, list2);
  k_conv1s<<<512, 256, 0, stream>>>(x, w1, idx1, h1c);
  k_conv2m<<<1024, 256, 0, stream>>>(h1c, w2b, idx1, list2, counter2, h2c);
  k_conv3m<<<768, 256, 0, stream>>>(h2c, w3b, idx2, list2, counter2, pooled);
  k_final<<<16, 128, 0, stream>>>(pooled, cnt, wl, bl, out);
}